// Round 1
// baseline (5401.591 us; speedup 1.0000x reference)
//
#include <hip/hip_runtime.h>
#include <cstddef>

static constexpr int NV = 100000;   // vertices
static constexpr int ME = 25000;    // hyperedges
static constexpr int KE = 16;       // vertices per edge
static constexpr float BN_EPS = 1e-5f;

__device__ __forceinline__ float sigm(float x) { return 1.0f / (1.0f + expf(-x)); }

// ---------------- GEMM: C = A[N,IC] @ W[OC,IC]^T + bias (+= if accf) ----------
__global__ __launch_bounds__(256)
void gemm_bias_kernel(const float* __restrict__ A, const float* __restrict__ W,
                      const float* __restrict__ bias, float* __restrict__ C,
                      int N, int IC, int OC, int accf)
{
    __shared__ float As[16][68];
    __shared__ float Ws[16][68];
    const int bm = blockIdx.x * 64;
    const int bn = blockIdx.y * 64;
    const int tid = threadIdx.x;
    const int tx = tid & 15;
    const int ty = tid >> 4;
    const int lr = tid >> 2;
    const int lk = (tid & 3) << 2;

    float acc[4][4] = {};

    for (int k0 = 0; k0 < IC; k0 += 16) {
        int ar = bm + lr;
        float4 av = make_float4(0.f, 0.f, 0.f, 0.f);
        if (ar < N) av = *reinterpret_cast<const float4*>(&A[(size_t)ar * IC + k0 + lk]);
        As[lk + 0][lr] = av.x; As[lk + 1][lr] = av.y; As[lk + 2][lr] = av.z; As[lk + 3][lr] = av.w;
        int wr = bn + lr;
        float4 wv = make_float4(0.f, 0.f, 0.f, 0.f);
        if (wr < OC) wv = *reinterpret_cast<const float4*>(&W[(size_t)wr * IC + k0 + lk]);
        Ws[lk + 0][lr] = wv.x; Ws[lk + 1][lr] = wv.y; Ws[lk + 2][lr] = wv.z; Ws[lk + 3][lr] = wv.w;
        __syncthreads();
        #pragma unroll
        for (int kk = 0; kk < 16; ++kk) {
            const float4 a = *reinterpret_cast<const float4*>(&As[kk][ty << 2]);
            const float4 w = *reinterpret_cast<const float4*>(&Ws[kk][tx << 2]);
            float av4[4] = {a.x, a.y, a.z, a.w};
            float wv4[4] = {w.x, w.y, w.z, w.w};
            #pragma unroll
            for (int i = 0; i < 4; ++i)
                #pragma unroll
                for (int j = 0; j < 4; ++j)
                    acc[i][j] = fmaf(av4[i], wv4[j], acc[i][j]);
        }
        __syncthreads();
    }
    const int row0 = bm + (ty << 2);
    const int col0 = bn + (tx << 2);
    #pragma unroll
    for (int i = 0; i < 4; ++i) {
        int r = row0 + i;
        if (r >= N) continue;
        #pragma unroll
        for (int j = 0; j < 4; ++j) {
            int c = col0 + j;
            if (c >= OC) continue;
            size_t o = (size_t)r * OC + c;
            float v = acc[i][j] + bias[c];
            if (accf) v += C[o];
            C[o] = v;
        }
    }
}

// -------- per-channel sum / sumsq over rows; blockDim.x == C (128 or 512) -----
__global__ void colstats_kernel(const float* __restrict__ X, int N, int C,
                                float* __restrict__ s1, float* __restrict__ s2,
                                int rowsPerBlock)
{
    const int c = threadIdx.x;
    int r0 = blockIdx.x * rowsPerBlock;
    int r1 = min(N, r0 + rowsPerBlock);
    float a = 0.f, b = 0.f;
    for (int r = r0; r < r1; ++r) {
        float v = X[(size_t)r * C + c];
        a += v;
        b += v * v;
    }
    atomicAdd(&s1[c], a);
    atomicAdd(&s2[c], b);
}

// -------- stats for C == 2 ----------------------------------------------------
__global__ void colstats2_kernel(const float* __restrict__ X, int N,
                                 float* __restrict__ s1, float* __restrict__ s2)
{
    __shared__ float red[256][4];
    int t = threadIdx.x;
    float a0 = 0, a1 = 0, b0 = 0, b1 = 0;
    for (int r = blockIdx.x * 256 + t; r < N; r += 256 * gridDim.x) {
        float x0 = X[2 * r], x1 = X[2 * r + 1];
        a0 += x0; b0 += x0 * x0;
        a1 += x1; b1 += x1 * x1;
    }
    red[t][0] = a0; red[t][1] = a1; red[t][2] = b0; red[t][3] = b1;
    __syncthreads();
    for (int s = 128; s > 0; s >>= 1) {
        if (t < s)
            for (int j = 0; j < 4; ++j) red[t][j] += red[t + s][j];
        __syncthreads();
    }
    if (t == 0) {
        atomicAdd(&s1[0], red[0][0]);
        atomicAdd(&s1[1], red[0][1]);
        atomicAdd(&s2[0], red[0][2]);
        atomicAdd(&s2[1], red[0][3]);
    }
}

__global__ void bn_finalize_kernel(const float* __restrict__ s1, const float* __restrict__ s2,
                                   const float* __restrict__ g, const float* __restrict__ bt,
                                   float* __restrict__ scale, float* __restrict__ shift,
                                   int C, float invN)
{
    int c = threadIdx.x;
    if (c < C) {
        float m = s1[c] * invN;
        float v = fmaxf(s2[c] * invN - m * m, 0.f);
        float sc = g[c] * rsqrtf(v + BN_EPS);
        scale[c] = sc;
        shift[c] = bt[c] - m * sc;
    }
}

// -------- edge gather with fused BN: ef[e,c] = (w_e/K)*(scale*Σ_k x + K*shift) -
__global__ void edge_gather_kernel(const float* __restrict__ X, const int* __restrict__ vidx,
                                   const float* __restrict__ we, const float* __restrict__ scale,
                                   const float* __restrict__ shift, float* __restrict__ ef, int C)
{
    const int e = blockIdx.x;
    const int c = threadIdx.x;
    float s = 0.f;
    #pragma unroll
    for (int k = 0; k < KE; ++k) {
        int v = vidx[e * KE + k];
        s += X[(size_t)v * C + c];
    }
    ef[(size_t)e * C + c] = (we[e] * (1.0f / KE)) * (scale[c] * s + (float)KE * shift[c]);
}

__global__ void edge_gather2_kernel(const float* __restrict__ X, const int* __restrict__ vidx,
                                    const float* __restrict__ we, const float* __restrict__ scale,
                                    const float* __restrict__ shift, float* __restrict__ ef)
{
    int e = blockIdx.x * blockDim.x + threadIdx.x;
    if (e >= ME) return;
    float s0 = 0.f, s1v = 0.f;
    #pragma unroll
    for (int k = 0; k < KE; ++k) {
        int v = vidx[e * KE + k];
        s0 += X[2 * v];
        s1v += X[2 * v + 1];
    }
    float w = we[e] * (1.0f / KE);
    ef[2 * e]     = w * (scale[0] * s0 + (float)KE * shift[0]);
    ef[2 * e + 1] = w * (scale[1] * s1v + (float)KE * shift[1]);
}

// -------- scatter-add ef into vertex buffer -----------------------------------
__global__ void scatter_add_kernel(const float* __restrict__ ef, const int* __restrict__ vidx,
                                   float* __restrict__ out, int C)
{
    const int e = blockIdx.x;
    const int c = threadIdx.x;
    float val = ef[(size_t)e * C + c];
    #pragma unroll
    for (int k = 0; k < KE; ++k) {
        int v = vidx[e * KE + k];
        atomicAdd(&out[(size_t)v * C + c], val);
    }
}

__global__ void scatter_add2_kernel(const float* __restrict__ ef, const int* __restrict__ vidx,
                                    float* __restrict__ out)
{
    int e = blockIdx.x * blockDim.x + threadIdx.x;
    if (e >= ME) return;
    float v0 = ef[2 * e], v1 = ef[2 * e + 1];
    #pragma unroll
    for (int k = 0; k < KE; ++k) {
        int v = vidx[e * KE + k];
        atomicAdd(&out[2 * v], v0);
        atomicAdd(&out[2 * v + 1], v1);
    }
}

__global__ void deg_kernel(const int* __restrict__ vidx, int* __restrict__ deg)
{
    int i = blockIdx.x * blockDim.x + threadIdx.x;
    if (i < ME * KE) atomicAdd(&deg[vidx[i]], 1);
}

// -------- divide by deg (+ optional relu) -------------------------------------
__global__ void vdiv_kernel(float* __restrict__ out, const int* __restrict__ deg,
                            int total, int log2C, int relu)
{
    int i = blockIdx.x * blockDim.x + threadIdx.x;
    int stride = gridDim.x * blockDim.x;
    for (; i < total; i += stride) {
        int v = i >> log2C;
        int d = deg[v];
        float dd = (float)(d < 1 ? 1 : d);
        float val = out[i] / dd;
        if (relu) val = fmaxf(val, 0.f);
        out[i] = val;
    }
}

// -------- GRU elementwise ------------------------------------------------------
__global__ void rx_kernel(const float* __restrict__ rpre, const float* __restrict__ xe,
                          float* __restrict__ rx, int n)
{
    int i = blockIdx.x * blockDim.x + threadIdx.x;
    if (i < n) rx[i] = sigm(rpre[i]) * xe[i];
}

__global__ void gru_out_kernel(const float* __restrict__ zpre, const float* __restrict__ opre,
                               const float* __restrict__ xe, float* __restrict__ outs, int n)
{
    int i = blockIdx.x * blockDim.x + threadIdx.x;
    if (i < n) {
        float z = sigm(zpre[i]);
        outs[i] = z * tanhf(opre[i]) + (1.f - z) * xe[i];
    }
}

// -------- attention pooling ----------------------------------------------------
__global__ void att_finalize_kernel(const float* __restrict__ s1, const float* __restrict__ s2,
                                    float* __restrict__ mu, float* __restrict__ qd, int C)
{
    int c = threadIdx.x;
    if (c < C) {
        float m = s1[c] / (float)NV;
        float vv = fmaxf((s2[c] - (float)NV * m * m) / (float)(NV - 1), 0.f);
        mu[c] = m;
        qd[c] = 1.0f / (4.0f * (vv + 0.001f));
    }
}

__global__ void proto_kernel(const float* __restrict__ outs, const float* __restrict__ mu,
                             const float* __restrict__ qd, float* __restrict__ proto,
                             int rowsPerBlock)
{
    const int c = threadIdx.x;  // C = 128
    int r0 = blockIdx.x * rowsPerBlock;
    int r1 = min(NV, r0 + rowsPerBlock);
    float m = mu[c], q = qd[c], acc = 0.f;
    for (int r = r0; r < r1; ++r) {
        float x = outs[(size_t)r * 128 + c];
        float dd = (x - m) * (x - m);
        acc += x * sigm(dd * q + 0.5f);
    }
    atomicAdd(&proto[c], acc);
}

// ==============================================================================
extern "C" void kernel_launch(void* const* d_in, const int* in_sizes, int n_in,
                              void* d_out, int out_size, void* d_ws, size_t ws_size,
                              hipStream_t stream)
{
    const float* X      = (const float*)d_in[0];
    const int*   vidx   = (const int*)  d_in[1];
    const float* we     = (const float*)d_in[2];
    const float* enc1_W = (const float*)d_in[3];  const float* enc1_b = (const float*)d_in[4];
    const float* enc2_W = (const float*)d_in[5];  const float* enc2_b = (const float*)d_in[6];
    const float* fc_W   = (const float*)d_in[7];  const float* fc_b   = (const float*)d_in[8];
    const float* f1u_W  = (const float*)d_in[9];  const float* f1u_b  = (const float*)d_in[10];
    const float* f2u_W  = (const float*)d_in[11]; const float* f2u_b  = (const float*)d_in[12];
    const float* f1r_W  = (const float*)d_in[13]; const float* f1r_b  = (const float*)d_in[14];
    const float* f2r_W  = (const float*)d_in[15]; const float* f2r_b  = (const float*)d_in[16];
    const float* f1_W   = (const float*)d_in[17]; const float* f1_b   = (const float*)d_in[18];
    const float* f2_W   = (const float*)d_in[19]; const float* f2_b   = (const float*)d_in[20];
    const float* dis1_W = (const float*)d_in[21]; const float* dis1_b = (const float*)d_in[22];
    const float* dis2_W = (const float*)d_in[23]; const float* dis2_b = (const float*)d_in[24];
    const float* dec1_W = (const float*)d_in[25]; const float* dec1_b = (const float*)d_in[26];
    const float* dec2_W = (const float*)d_in[27]; const float* dec2_b = (const float*)d_in[28];
    const float* enc1_g = (const float*)d_in[29]; const float* enc1_bt = (const float*)d_in[30];
    const float* enc2_g = (const float*)d_in[31]; const float* enc2_bt = (const float*)d_in[32];
    const float* dis1_g = (const float*)d_in[33]; const float* dis1_bt = (const float*)d_in[34];
    const float* dis2_g = (const float*)d_in[35]; const float* dis2_bt = (const float*)d_in[36];
    const float* dec1_g = (const float*)d_in[37]; const float* dec1_bt = (const float*)d_in[38];
    const float* dec2_g = (const float*)d_in[39]; const float* dec2_bt = (const float*)d_in[40];

    float* out   = (float*)d_out;
    float* outs  = out;                   // [N,128]
    float* x_de  = out + 12800000;        // [N,128]
    float* proto = out + 25600000;        // [128]
    float* xdis  = out + 25600128;        // [N,2]

    float* ws   = (float*)d_ws;
    float* bufA = ws;                     // [N,512]  (x1 / GRU temps / hdis / hdec)
    float* bufE = ws + 51200000;          // [M,512]  edge features
    float* t0   = ws + 64000000;          // [N,128]
    float* t1   = ws + 76800000;          // [N,128]
    float* s1   = ws + 89600000;          // [512]
    float* s2   = s1 + 512;               // [512]
    float* scl  = s2 + 512;               // [512]
    float* shf  = scl + 512;              // [512]
    int*   deg  = (int*)(shf + 512);      // [N]

    const int n128 = NV * 128;

    auto gemm = [&](const float* A, const float* W, const float* b, float* Cq,
                    int ic, int oc, int accf) {
        dim3 g((NV + 63) / 64, (oc + 63) / 64);
        gemm_bias_kernel<<<g, 256, 0, stream>>>(A, W, b, Cq, NV, ic, oc, accf);
    };

    auto bn_v2v = [&](const float* pre, int C, const float* g_, const float* bt_,
                      int relu, float* target) {
        hipMemsetAsync(s1, 0, 2 * 512 * sizeof(float), stream);
        colstats_kernel<<<400, C, 0, stream>>>(pre, NV, C, s1, s2, 250);
        bn_finalize_kernel<<<1, 512, 0, stream>>>(s1, s2, g_, bt_, scl, shf, C, 1.0f / NV);
        edge_gather_kernel<<<ME, C, 0, stream>>>(pre, vidx, we, scl, shf, bufE, C);
        hipMemsetAsync(target, 0, (size_t)NV * C * sizeof(float), stream);
        scatter_add_kernel<<<ME, C, 0, stream>>>(bufE, vidx, target, C);
        int log2c = (C == 512) ? 9 : 7;
        vdiv_kernel<<<2048, 256, 0, stream>>>(target, deg, NV * C, log2c, relu);
    };

    // ---- degree (shared by all v2v) ----
    hipMemsetAsync(deg, 0, NV * sizeof(int), stream);
    deg_kernel<<<(ME * KE + 255) / 256, 256, 0, stream>>>(vidx, deg);

    // ---- conv1 (enc1): x1 = bufA ----
    gemm(X, enc1_W, enc1_b, bufA, 128, 512, 0);
    bn_v2v(bufA, 512, enc1_g, enc1_bt, 1, bufA);

    // ---- conv2 (enc2): xe = t0 ----
    gemm(bufA, enc2_W, enc2_b, t0, 512, 128, 0);
    bn_v2v(t0, 128, enc2_g, enc2_bt, 0, t0);

    // ---- xe1 = x1 @ fc^T + b : t1 ----
    gemm(bufA, fc_W, fc_b, t1, 512, 128, 0);

    // ---- GRU gating (bufA free -> 3 temp [N,128] regions) ----
    float* g0 = bufA;
    float* g1 = bufA + 12800000;
    float* g2 = bufA + 25600000;
    gemm(t1, f1u_W, f1u_b, g0, 128, 128, 0);
    gemm(t0, f2u_W, f2u_b, g0, 128, 128, 1);
    gemm(t1, f1r_W, f1r_b, g1, 128, 128, 0);
    gemm(t0, f2r_W, f2r_b, g1, 128, 128, 1);
    rx_kernel<<<(n128 + 255) / 256, 256, 0, stream>>>(g1, t0, g1, n128);
    gemm(t1, f1_W, f1_b, g2, 128, 128, 0);
    gemm(g1, f2_W, f2_b, g2, 128, 128, 1);
    gru_out_kernel<<<(n128 + 255) / 256, 256, 0, stream>>>(g0, g2, t0, outs, n128);

    // ---- attention pooling -> proto ----
    hipMemsetAsync(s1, 0, 2 * 512 * sizeof(float), stream);
    colstats_kernel<<<400, 128, 0, stream>>>(outs, NV, 128, s1, s2, 250);
    att_finalize_kernel<<<1, 128, 0, stream>>>(s1, s2, scl, shf, 128);
    hipMemsetAsync(proto, 0, 128 * sizeof(float), stream);
    proto_kernel<<<400, 128, 0, stream>>>(outs, scl, shf, proto, 250);

    // ---- discriminator branch ----
    gemm(outs, dis1_W, dis1_b, bufA, 128, 512, 0);
    bn_v2v(bufA, 512, dis1_g, dis1_bt, 1, bufA);           // hdis = bufA
    gemm(bufA, dis2_W, dis2_b, t0, 512, 2, 0);             // [N,2] pre
    hipMemsetAsync(s1, 0, 2 * 512 * sizeof(float), stream);
    colstats2_kernel<<<64, 256, 0, stream>>>(t0, NV, s1, s2);
    bn_finalize_kernel<<<1, 512, 0, stream>>>(s1, s2, dis2_g, dis2_bt, scl, shf, 2, 1.0f / NV);
    edge_gather2_kernel<<<(ME + 255) / 256, 256, 0, stream>>>(t0, vidx, we, scl, shf, bufE);
    hipMemsetAsync(xdis, 0, 200000 * sizeof(float), stream);
    scatter_add2_kernel<<<(ME + 255) / 256, 256, 0, stream>>>(bufE, vidx, xdis);
    vdiv_kernel<<<512, 256, 0, stream>>>(xdis, deg, 200000, 1, 0);

    // ---- decoder branch ----
    gemm(outs, dec1_W, dec1_b, bufA, 128, 512, 0);
    bn_v2v(bufA, 512, dec1_g, dec1_bt, 1, bufA);           // hdec = bufA
    gemm(bufA, dec2_W, dec2_b, t0, 512, 128, 0);
    hipMemsetAsync(s1, 0, 2 * 512 * sizeof(float), stream);
    colstats_kernel<<<400, 128, 0, stream>>>(t0, NV, 128, s1, s2, 250);
    bn_finalize_kernel<<<1, 512, 0, stream>>>(s1, s2, dec2_g, dec2_bt, scl, shf, 128, 1.0f / NV);
    edge_gather_kernel<<<ME, 128, 0, stream>>>(t0, vidx, we, scl, shf, bufE, 128);
    hipMemsetAsync(x_de, 0, (size_t)n128 * sizeof(float), stream);
    scatter_add_kernel<<<ME, 128, 0, stream>>>(bufE, vidx, x_de, 128);
    vdiv_kernel<<<2048, 256, 0, stream>>>(x_de, deg, n128, 7, 0);
}

// Round 2
// 3346.285 us; speedup vs baseline: 1.6142x; 1.6142x over previous
//
#include <hip/hip_runtime.h>
#include <cstddef>

static constexpr int NV = 100000;   // vertices
static constexpr int ME = 25000;    // hyperedges
static constexpr int KE = 16;       // vertices per edge
static constexpr float BN_EPS = 1e-5f;

__device__ __forceinline__ float sigm(float x) { return 1.0f / (1.0f + expf(-x)); }

// ---------------- GEMM: C = A[N,IC] @ W[OC,IC]^T + bias (+= if accf) ----------
__global__ __launch_bounds__(256)
void gemm_bias_kernel(const float* __restrict__ A, const float* __restrict__ W,
                      const float* __restrict__ bias, float* __restrict__ C,
                      int N, int IC, int OC, int accf)
{
    __shared__ float As[16][68];
    __shared__ float Ws[16][68];
    const int bm = blockIdx.x * 64;
    const int bn = blockIdx.y * 64;
    const int tid = threadIdx.x;
    const int tx = tid & 15;
    const int ty = tid >> 4;
    const int lr = tid >> 2;
    const int lk = (tid & 3) << 2;

    float acc[4][4] = {};

    for (int k0 = 0; k0 < IC; k0 += 16) {
        int ar = bm + lr;
        float4 av = make_float4(0.f, 0.f, 0.f, 0.f);
        if (ar < N) av = *reinterpret_cast<const float4*>(&A[(size_t)ar * IC + k0 + lk]);
        As[lk + 0][lr] = av.x; As[lk + 1][lr] = av.y; As[lk + 2][lr] = av.z; As[lk + 3][lr] = av.w;
        int wr = bn + lr;
        float4 wv = make_float4(0.f, 0.f, 0.f, 0.f);
        if (wr < OC) wv = *reinterpret_cast<const float4*>(&W[(size_t)wr * IC + k0 + lk]);
        Ws[lk + 0][lr] = wv.x; Ws[lk + 1][lr] = wv.y; Ws[lk + 2][lr] = wv.z; Ws[lk + 3][lr] = wv.w;
        __syncthreads();
        #pragma unroll
        for (int kk = 0; kk < 16; ++kk) {
            const float4 a = *reinterpret_cast<const float4*>(&As[kk][ty << 2]);
            const float4 w = *reinterpret_cast<const float4*>(&Ws[kk][tx << 2]);
            float av4[4] = {a.x, a.y, a.z, a.w};
            float wv4[4] = {w.x, w.y, w.z, w.w};
            #pragma unroll
            for (int i = 0; i < 4; ++i)
                #pragma unroll
                for (int j = 0; j < 4; ++j)
                    acc[i][j] = fmaf(av4[i], wv4[j], acc[i][j]);
        }
        __syncthreads();
    }
    const int row0 = bm + (ty << 2);
    const int col0 = bn + (tx << 2);
    #pragma unroll
    for (int i = 0; i < 4; ++i) {
        int r = row0 + i;
        if (r >= N) continue;
        #pragma unroll
        for (int j = 0; j < 4; ++j) {
            int c = col0 + j;
            if (c >= OC) continue;
            size_t o = (size_t)r * OC + c;
            float v = acc[i][j] + bias[c];
            if (accf) v += C[o];
            C[o] = v;
        }
    }
}

// -------- per-channel sum / sumsq over rows; blockDim.x == C (128 or 512) -----
__global__ void colstats_kernel(const float* __restrict__ X, int N, int C,
                                float* __restrict__ s1, float* __restrict__ s2,
                                int rowsPerBlock)
{
    const int c = threadIdx.x;
    int r0 = blockIdx.x * rowsPerBlock;
    int r1 = min(N, r0 + rowsPerBlock);
    float a = 0.f, b = 0.f;
    for (int r = r0; r < r1; ++r) {
        float v = X[(size_t)r * C + c];
        a += v;
        b += v * v;
    }
    atomicAdd(&s1[c], a);
    atomicAdd(&s2[c], b);
}

// -------- stats for C == 2 ----------------------------------------------------
__global__ void colstats2_kernel(const float* __restrict__ X, int N,
                                 float* __restrict__ s1, float* __restrict__ s2)
{
    __shared__ float red[256][4];
    int t = threadIdx.x;
    float a0 = 0, a1 = 0, b0 = 0, b1 = 0;
    for (int r = blockIdx.x * 256 + t; r < N; r += 256 * gridDim.x) {
        float x0 = X[2 * r], x1 = X[2 * r + 1];
        a0 += x0; b0 += x0 * x0;
        a1 += x1; b1 += x1 * x1;
    }
    red[t][0] = a0; red[t][1] = a1; red[t][2] = b0; red[t][3] = b1;
    __syncthreads();
    for (int s = 128; s > 0; s >>= 1) {
        if (t < s)
            for (int j = 0; j < 4; ++j) red[t][j] += red[t + s][j];
        __syncthreads();
    }
    if (t == 0) {
        atomicAdd(&s1[0], red[0][0]);
        atomicAdd(&s1[1], red[0][1]);
        atomicAdd(&s2[0], red[0][2]);
        atomicAdd(&s2[1], red[0][3]);
    }
}

__global__ void bn_finalize_kernel(const float* __restrict__ s1, const float* __restrict__ s2,
                                   const float* __restrict__ g, const float* __restrict__ bt,
                                   float* __restrict__ scale, float* __restrict__ shift,
                                   int C, float invN)
{
    int c = threadIdx.x;
    if (c < C) {
        float m = s1[c] * invN;
        float v = fmaxf(s2[c] * invN - m * m, 0.f);
        float sc = g[c] * rsqrtf(v + BN_EPS);
        scale[c] = sc;
        shift[c] = bt[c] - m * sc;
    }
}

// -------- edge gather with fused BN: ef[e,c] = (w_e/K)*(scale*Σ_k x + K*shift) -
__global__ void edge_gather_kernel(const float* __restrict__ X, const int* __restrict__ vidx,
                                   const float* __restrict__ we, const float* __restrict__ scale,
                                   const float* __restrict__ shift, float* __restrict__ ef, int C)
{
    const int e = blockIdx.x;
    const int c = threadIdx.x;
    float s = 0.f;
    #pragma unroll
    for (int k = 0; k < KE; ++k) {
        int v = vidx[e * KE + k];
        s += X[(size_t)v * C + c];
    }
    ef[(size_t)e * C + c] = (we[e] * (1.0f / KE)) * (scale[c] * s + (float)KE * shift[c]);
}

__global__ void edge_gather2_kernel(const float* __restrict__ X, const int* __restrict__ vidx,
                                    const float* __restrict__ we, const float* __restrict__ scale,
                                    const float* __restrict__ shift, float* __restrict__ ef)
{
    int e = blockIdx.x * blockDim.x + threadIdx.x;
    if (e >= ME) return;
    float s0 = 0.f, s1v = 0.f;
    #pragma unroll
    for (int k = 0; k < KE; ++k) {
        int v = vidx[e * KE + k];
        s0 += X[2 * v];
        s1v += X[2 * v + 1];
    }
    float w = we[e] * (1.0f / KE);
    ef[2 * e]     = w * (scale[0] * s0 + (float)KE * shift[0]);
    ef[2 * e + 1] = w * (scale[1] * s1v + (float)KE * shift[1]);
}

// ================= CSR build =================================================
__global__ void deg_kernel(const int* __restrict__ vidx, int* __restrict__ deg)
{
    int i = blockIdx.x * blockDim.x + threadIdx.x;
    if (i < ME * KE) atomicAdd(&deg[vidx[i]], 1);
}

__global__ void scan_block_kernel(const int* __restrict__ deg, int* __restrict__ rowptr,
                                  int* __restrict__ blocksums, int n)
{
    __shared__ int tmp[256];
    int i = blockIdx.x * 256 + threadIdx.x;
    int v = (i < n) ? deg[i] : 0;
    tmp[threadIdx.x] = v;
    __syncthreads();
    for (int off = 1; off < 256; off <<= 1) {
        int t = (threadIdx.x >= off) ? tmp[threadIdx.x - off] : 0;
        __syncthreads();
        tmp[threadIdx.x] += t;
        __syncthreads();
    }
    if (i < n) rowptr[i] = tmp[threadIdx.x] - v;   // exclusive within block
    if (threadIdx.x == 255) blocksums[blockIdx.x] = tmp[255];
}

__global__ void scan_sums_kernel(int* __restrict__ blocksums, int nb)
{
    if (threadIdx.x == 0 && blockIdx.x == 0) {
        int acc = 0;
        for (int b = 0; b < nb; ++b) { int t = blocksums[b]; blocksums[b] = acc; acc += t; }
    }
}

__global__ void scan_add_kernel(int* __restrict__ rowptr, const int* __restrict__ blocksums, int n)
{
    int i = blockIdx.x * 256 + threadIdx.x;
    if (i < n) rowptr[i] += blocksums[blockIdx.x];
    if (i == 0) rowptr[n] = ME * KE;
}

__global__ void csr_fill_kernel(const int* __restrict__ vidx, int* __restrict__ cursor,
                                int* __restrict__ csr)
{
    int i = blockIdx.x * blockDim.x + threadIdx.x;
    if (i < ME * KE) {
        int v = vidx[i];
        int pos = atomicAdd(&cursor[v], 1);
        csr[pos] = i >> 4;   // edge id
    }
}

// -------- e->v via CSR gather, fused /deg (+relu). C4 = C/4 lanes per vertex --
__global__ __launch_bounds__(256)
void csr_gather_kernel(const float* __restrict__ ef, const int* __restrict__ rowptr,
                       const int* __restrict__ csr, float* __restrict__ outp,
                       int log2C4, int relu)
{
    const int C4 = 1 << log2C4;
    const int vpb = 256 >> log2C4;
    const int v = blockIdx.x * vpb + (threadIdx.x >> log2C4);
    const int lane = threadIdx.x & (C4 - 1);
    if (v >= NV) return;
    const int s = rowptr[v], e = rowptr[v + 1];
    float4 acc = make_float4(0.f, 0.f, 0.f, 0.f);
    const float4* ef4 = (const float4*)ef;
    for (int i = s; i < e; ++i) {
        int ed = csr[i];
        float4 t = ef4[(size_t)ed * C4 + lane];
        acc.x += t.x; acc.y += t.y; acc.z += t.z; acc.w += t.w;
    }
    float inv = 1.0f / (float)max(e - s, 1);
    acc.x *= inv; acc.y *= inv; acc.z *= inv; acc.w *= inv;
    if (relu) {
        acc.x = fmaxf(acc.x, 0.f); acc.y = fmaxf(acc.y, 0.f);
        acc.z = fmaxf(acc.z, 0.f); acc.w = fmaxf(acc.w, 0.f);
    }
    ((float4*)outp)[(size_t)v * C4 + lane] = acc;
}

__global__ void csr_gather2_kernel(const float* __restrict__ ef, const int* __restrict__ rowptr,
                                   const int* __restrict__ csr, float* __restrict__ outp)
{
    int v = blockIdx.x * blockDim.x + threadIdx.x;
    if (v >= NV) return;
    int s = rowptr[v], e = rowptr[v + 1];
    float a0 = 0.f, a1 = 0.f;
    for (int i = s; i < e; ++i) {
        int ed = csr[i];
        a0 += ef[2 * ed];
        a1 += ef[2 * ed + 1];
    }
    float inv = 1.0f / (float)max(e - s, 1);
    outp[2 * v]     = a0 * inv;
    outp[2 * v + 1] = a1 * inv;
}

// -------- GRU elementwise ------------------------------------------------------
__global__ void rx_kernel(const float* __restrict__ rpre, const float* __restrict__ xe,
                          float* __restrict__ rx, int n)
{
    int i = blockIdx.x * blockDim.x + threadIdx.x;
    if (i < n) rx[i] = sigm(rpre[i]) * xe[i];
}

__global__ void gru_out_kernel(const float* __restrict__ zpre, const float* __restrict__ opre,
                               const float* __restrict__ xe, float* __restrict__ outs, int n)
{
    int i = blockIdx.x * blockDim.x + threadIdx.x;
    if (i < n) {
        float z = sigm(zpre[i]);
        outs[i] = z * tanhf(opre[i]) + (1.f - z) * xe[i];
    }
}

// -------- attention pooling ----------------------------------------------------
__global__ void att_finalize_kernel(const float* __restrict__ s1, const float* __restrict__ s2,
                                    float* __restrict__ mu, float* __restrict__ qd, int C)
{
    int c = threadIdx.x;
    if (c < C) {
        float m = s1[c] / (float)NV;
        float vv = fmaxf((s2[c] - (float)NV * m * m) / (float)(NV - 1), 0.f);
        mu[c] = m;
        qd[c] = 1.0f / (4.0f * (vv + 0.001f));
    }
}

__global__ void proto_kernel(const float* __restrict__ outs, const float* __restrict__ mu,
                             const float* __restrict__ qd, float* __restrict__ proto,
                             int rowsPerBlock)
{
    const int c = threadIdx.x;  // C = 128
    int r0 = blockIdx.x * rowsPerBlock;
    int r1 = min(NV, r0 + rowsPerBlock);
    float m = mu[c], q = qd[c], acc = 0.f;
    for (int r = r0; r < r1; ++r) {
        float x = outs[(size_t)r * 128 + c];
        float dd = (x - m) * (x - m);
        acc += x * sigm(dd * q + 0.5f);
    }
    atomicAdd(&proto[c], acc);
}

// ==============================================================================
extern "C" void kernel_launch(void* const* d_in, const int* in_sizes, int n_in,
                              void* d_out, int out_size, void* d_ws, size_t ws_size,
                              hipStream_t stream)
{
    const float* X      = (const float*)d_in[0];
    const int*   vidx   = (const int*)  d_in[1];
    const float* we     = (const float*)d_in[2];
    const float* enc1_W = (const float*)d_in[3];  const float* enc1_b = (const float*)d_in[4];
    const float* enc2_W = (const float*)d_in[5];  const float* enc2_b = (const float*)d_in[6];
    const float* fc_W   = (const float*)d_in[7];  const float* fc_b   = (const float*)d_in[8];
    const float* f1u_W  = (const float*)d_in[9];  const float* f1u_b  = (const float*)d_in[10];
    const float* f2u_W  = (const float*)d_in[11]; const float* f2u_b  = (const float*)d_in[12];
    const float* f1r_W  = (const float*)d_in[13]; const float* f1r_b  = (const float*)d_in[14];
    const float* f2r_W  = (const float*)d_in[15]; const float* f2r_b  = (const float*)d_in[16];
    const float* f1_W   = (const float*)d_in[17]; const float* f1_b   = (const float*)d_in[18];
    const float* f2_W   = (const float*)d_in[19]; const float* f2_b   = (const float*)d_in[20];
    const float* dis1_W = (const float*)d_in[21]; const float* dis1_b = (const float*)d_in[22];
    const float* dis2_W = (const float*)d_in[23]; const float* dis2_b = (const float*)d_in[24];
    const float* dec1_W = (const float*)d_in[25]; const float* dec1_b = (const float*)d_in[26];
    const float* dec2_W = (const float*)d_in[27]; const float* dec2_b = (const float*)d_in[28];
    const float* enc1_g = (const float*)d_in[29]; const float* enc1_bt = (const float*)d_in[30];
    const float* enc2_g = (const float*)d_in[31]; const float* enc2_bt = (const float*)d_in[32];
    const float* dis1_g = (const float*)d_in[33]; const float* dis1_bt = (const float*)d_in[34];
    const float* dis2_g = (const float*)d_in[35]; const float* dis2_bt = (const float*)d_in[36];
    const float* dec1_g = (const float*)d_in[37]; const float* dec1_bt = (const float*)d_in[38];
    const float* dec2_g = (const float*)d_in[39]; const float* dec2_bt = (const float*)d_in[40];

    float* out   = (float*)d_out;
    float* outs  = out;                   // [N,128]
    float* x_de  = out + 12800000;        // [N,128]
    float* proto = out + 25600000;        // [128]
    float* xdis  = out + 25600128;        // [N,2]

    float* ws   = (float*)d_ws;
    float* bufA = ws;                     // [N,512]  (x1 / GRU temps / hdis / hdec)
    float* bufE = ws + 51200000;          // [M,512]  edge features
    float* t0   = ws + 64000000;          // [N,128]
    float* t1   = ws + 76800000;          // [N,128]
    float* s1   = ws + 89600000;          // [512]
    float* s2   = s1 + 512;               // [512]
    float* scl  = s2 + 512;               // [512]
    float* shf  = scl + 512;              // [512]
    int*   deg     = (int*)(shf + 512);   // [N]
    int*   rowptr  = deg + NV;            // [N+1]
    int*   cursor  = rowptr + NV + 1;     // [N]
    int*   bsums   = cursor + NV;         // [512]
    int*   csr     = bsums + 512;         // [M*K]

    const int n128 = NV * 128;
    const int nScanBlocks = (NV + 255) / 256;   // 391

    auto gemm = [&](const float* A, const float* W, const float* b, float* Cq,
                    int ic, int oc, int accf) {
        dim3 g((NV + 63) / 64, (oc + 63) / 64);
        gemm_bias_kernel<<<g, 256, 0, stream>>>(A, W, b, Cq, NV, ic, oc, accf);
    };

    auto bn_v2v = [&](const float* pre, int C, const float* g_, const float* bt_,
                      int relu, float* target) {
        hipMemsetAsync(s1, 0, 2 * 512 * sizeof(float), stream);
        colstats_kernel<<<400, C, 0, stream>>>(pre, NV, C, s1, s2, 250);
        bn_finalize_kernel<<<1, 512, 0, stream>>>(s1, s2, g_, bt_, scl, shf, C, 1.0f / NV);
        edge_gather_kernel<<<ME, C, 0, stream>>>(pre, vidx, we, scl, shf, bufE, C);
        int log2c4 = (C == 512) ? 7 : 5;
        int vpb = 256 >> log2c4;
        csr_gather_kernel<<<(NV + vpb - 1) / vpb, 256, 0, stream>>>(
            bufE, rowptr, csr, target, log2c4, relu);
    };

    // ---- build CSR (shared by all v2v calls) ----
    hipMemsetAsync(deg, 0, NV * sizeof(int), stream);
    deg_kernel<<<(ME * KE + 255) / 256, 256, 0, stream>>>(vidx, deg);
    scan_block_kernel<<<nScanBlocks, 256, 0, stream>>>(deg, rowptr, bsums, NV);
    scan_sums_kernel<<<1, 64, 0, stream>>>(bsums, nScanBlocks);
    scan_add_kernel<<<nScanBlocks, 256, 0, stream>>>(rowptr, bsums, NV);
    hipMemcpyAsync(cursor, rowptr, NV * sizeof(int), hipMemcpyDeviceToDevice, stream);
    csr_fill_kernel<<<(ME * KE + 255) / 256, 256, 0, stream>>>(vidx, cursor, csr);

    // ---- conv1 (enc1): x1 = bufA ----
    gemm(X, enc1_W, enc1_b, bufA, 128, 512, 0);
    bn_v2v(bufA, 512, enc1_g, enc1_bt, 1, bufA);

    // ---- conv2 (enc2): xe = t0 ----
    gemm(bufA, enc2_W, enc2_b, t0, 512, 128, 0);
    bn_v2v(t0, 128, enc2_g, enc2_bt, 0, t0);

    // ---- xe1 = x1 @ fc^T + b : t1 ----
    gemm(bufA, fc_W, fc_b, t1, 512, 128, 0);

    // ---- GRU gating (bufA free -> 3 temp [N,128] regions) ----
    float* g0 = bufA;
    float* g1 = bufA + 12800000;
    float* g2 = bufA + 25600000;
    gemm(t1, f1u_W, f1u_b, g0, 128, 128, 0);
    gemm(t0, f2u_W, f2u_b, g0, 128, 128, 1);
    gemm(t1, f1r_W, f1r_b, g1, 128, 128, 0);
    gemm(t0, f2r_W, f2r_b, g1, 128, 128, 1);
    rx_kernel<<<(n128 + 255) / 256, 256, 0, stream>>>(g1, t0, g1, n128);
    gemm(t1, f1_W, f1_b, g2, 128, 128, 0);
    gemm(g1, f2_W, f2_b, g2, 128, 128, 1);
    gru_out_kernel<<<(n128 + 255) / 256, 256, 0, stream>>>(g0, g2, t0, outs, n128);

    // ---- attention pooling -> proto ----
    hipMemsetAsync(s1, 0, 2 * 512 * sizeof(float), stream);
    colstats_kernel<<<400, 128, 0, stream>>>(outs, NV, 128, s1, s2, 250);
    att_finalize_kernel<<<1, 128, 0, stream>>>(s1, s2, scl, shf, 128);
    hipMemsetAsync(proto, 0, 128 * sizeof(float), stream);
    proto_kernel<<<400, 128, 0, stream>>>(outs, scl, shf, proto, 250);

    // ---- discriminator branch ----
    gemm(outs, dis1_W, dis1_b, bufA, 128, 512, 0);
    bn_v2v(bufA, 512, dis1_g, dis1_bt, 1, bufA);           // hdis = bufA
    gemm(bufA, dis2_W, dis2_b, t0, 512, 2, 0);             // [N,2] pre
    hipMemsetAsync(s1, 0, 2 * 512 * sizeof(float), stream);
    colstats2_kernel<<<64, 256, 0, stream>>>(t0, NV, s1, s2);
    bn_finalize_kernel<<<1, 512, 0, stream>>>(s1, s2, dis2_g, dis2_bt, scl, shf, 2, 1.0f / NV);
    edge_gather2_kernel<<<(ME + 255) / 256, 256, 0, stream>>>(t0, vidx, we, scl, shf, bufE);
    csr_gather2_kernel<<<(NV + 255) / 256, 256, 0, stream>>>(bufE, rowptr, csr, xdis);

    // ---- decoder branch ----
    gemm(outs, dec1_W, dec1_b, bufA, 128, 512, 0);
    bn_v2v(bufA, 512, dec1_g, dec1_bt, 1, bufA);           // hdec = bufA
    gemm(bufA, dec2_W, dec2_b, t0, 512, 128, 0);
    hipMemsetAsync(s1, 0, 2 * 512 * sizeof(float), stream);
    colstats_kernel<<<400, 128, 0, stream>>>(t0, NV, 128, s1, s2, 250);
    bn_finalize_kernel<<<1, 512, 0, stream>>>(s1, s2, dec2_g, dec2_bt, scl, shf, 128, 1.0f / NV);
    edge_gather_kernel<<<ME, 128, 0, stream>>>(t0, vidx, we, scl, shf, bufE, 128);
    csr_gather_kernel<<<(NV + 7) / 8, 256, 0, stream>>>(bufE, rowptr, csr, x_de, 5, 0);
}

// Round 3
// 1267.343 us; speedup vs baseline: 4.2621x; 2.6404x over previous
//
#include <hip/hip_runtime.h>
#include <cstddef>
#include <cstdint>

static constexpr int NV = 100000;   // vertices
static constexpr int NP = 100096;   // padded to 782*128
static constexpr int ME = 25000;    // hyperedges
static constexpr int KE = 16;       // vertices per edge
static constexpr float BN_EPS = 1e-5f;

typedef unsigned int u32;
typedef unsigned short ushortx;
typedef __attribute__((ext_vector_type(8))) short s16x8;
typedef __attribute__((ext_vector_type(8))) unsigned short u16x8;
typedef __attribute__((ext_vector_type(2))) unsigned short u16x2;
typedef __attribute__((ext_vector_type(4))) float f32x4;

__device__ __forceinline__ float sigm(float x) { return 1.0f / (1.0f + expf(-x)); }
__device__ __forceinline__ float bf2f(unsigned short u) {
    union { u32 i; float f; } v; v.i = ((u32)u) << 16; return v.f;
}
__device__ __forceinline__ unsigned short f2bf(float f) {
    union { float f; u32 i; } v; v.f = f;
    u32 u = v.i;
    return (unsigned short)((u + 0x7FFFu + ((u >> 16) & 1u)) >> 16);
}

#define GLD16(g, l) __builtin_amdgcn_global_load_lds(                          \
    (__attribute__((address_space(1))) const unsigned int*)(g),                \
    (__attribute__((address_space(3))) unsigned int*)(l), 16, 0, 0)

// ================= bf16 MFMA GEMM: C = A[NP,IC] @ W[OC,IC]^T + bias ==========
// BM=128, BN=64, 4 waves (2x2), 16x16x32 MFMA. Output bf16 (ldb, col offset).
// Optional fused column stats (sum, sumsq) over valid rows (< NV).
__global__ __launch_bounds__(256)
void mfma_gemm(const unsigned short* __restrict__ A, int IC,
               const unsigned short* __restrict__ W, const float* __restrict__ bias,
               unsigned short* __restrict__ Cb, int ldb, int cb0,
               float* __restrict__ s1f, float* __restrict__ s2f)
{
    __shared__ unsigned short smA[128 * 64];
    const int bm = blockIdx.y * 128;
    const int bn = blockIdx.x * 64;
    const int tid = threadIdx.x;
    const int l = tid & 63, w = tid >> 6;
    const int wrow = w >> 1, wcol = w & 1;

    f32x4 acc[4][2];
    #pragma unroll
    for (int m = 0; m < 4; ++m)
        #pragma unroll
        for (int n = 0; n < 2; ++n)
            #pragma unroll
            for (int r = 0; r < 4; ++r) acc[m][n][r] = 0.f;

    const int swz = (((l & 7) ^ (l >> 3)) << 3);   // ushort offset, inverse swizzle for source

    for (int k0 = 0; k0 < IC; k0 += 64) {
        // ---- stage A tile [128][64] bf16 into LDS (linear dest, swizzled source)
        #pragma unroll
        for (int i = 0; i < 4; ++i) {
            const unsigned short* g = A + (size_t)(bm + 32 * w + 8 * i + (l >> 3)) * IC + k0 + swz;
            GLD16(g, smA + 2048 * w + 512 * i);
        }
        // ---- B fragments direct from global (W is tiny, L2-hot)
        s16x8 bfr[2][2];
        #pragma unroll
        for (int n = 0; n < 2; ++n)
            #pragma unroll
            for (int ks = 0; ks < 2; ++ks) {
                int col = bn + wcol * 32 + n * 16 + (l & 15);
                bfr[n][ks] = *(const s16x8*)&W[(size_t)col * IC + k0 + ks * 32 + ((l >> 4) << 3)];
            }
        __syncthreads();
        #pragma unroll
        for (int ks = 0; ks < 2; ++ks) {
            s16x8 afr[4];
            #pragma unroll
            for (int m = 0; m < 4; ++m) {
                int row = wrow * 64 + m * 16 + (l & 15);
                int off = row * 64 + ((ks * 32 + ((l >> 4) << 3)) ^ ((l & 7) << 3));
                afr[m] = *(const s16x8*)&smA[off];
            }
            #pragma unroll
            for (int m = 0; m < 4; ++m)
                #pragma unroll
                for (int n = 0; n < 2; ++n)
                    acc[m][n] = __builtin_amdgcn_mfma_f32_16x16x32_bf16(
                        afr[m], bfr[n][ks], acc[m][n], 0, 0, 0);
        }
        __syncthreads();
    }

    // ---- epilogue: bias, bf16 store, fused column stats
    #pragma unroll
    for (int n = 0; n < 2; ++n) {
        const int col = bn + wcol * 32 + n * 16 + (l & 15);
        const float bs = bias[col];
        float ssum = 0.f, sq = 0.f;
        #pragma unroll
        for (int m = 0; m < 4; ++m) {
            const int row0 = bm + wrow * 64 + m * 16 + ((l >> 4) << 2);
            #pragma unroll
            for (int r = 0; r < 4; ++r) {
                float v = acc[m][n][r] + bs;
                int row = row0 + r;
                Cb[(size_t)row * ldb + cb0 + col] = f2bf(v);
                if (s1f && row < NV) { ssum += v; sq += v * v; }
            }
        }
        if (s1f) {
            ssum += __shfl_xor(ssum, 16); ssum += __shfl_xor(ssum, 32);
            sq   += __shfl_xor(sq, 16);   sq   += __shfl_xor(sq, 32);
            if ((l >> 4) == 0) {
                atomicAdd(&s1f[col], ssum);
                atomicAdd(&s2f[col], sq);
            }
        }
    }
}

// ================= weight prep: f32 -> bf16 (+ GRU weight/bias concat) ========
__global__ void prep_weights(const float* e1, const float* e2, const float* fcw,
                             const float* d1, const float* dc1, const float* dc2,
                             const float* ds2,
                             const float* f1u, const float* f2u,
                             const float* f1r, const float* f2r,
                             const float* f1, const float* f2,
                             const float* f1ub, const float* f2ub,
                             const float* f1rb, const float* f2rb,
                             const float* f1b, const float* f2b,
                             unsigned short* WB, float* bzr, float* bo)
{
    int i = blockIdx.x * 256 + threadIdx.x;
    if (i < 65536)           WB[i] = f2bf(e1[i]);
    else if (i < 131072)     WB[i] = f2bf(e2[i - 65536]);
    else if (i < 196608)     WB[i] = f2bf(fcw[i - 131072]);
    else if (i < 262144)     WB[i] = f2bf(d1[i - 196608]);
    else if (i < 327680)     WB[i] = f2bf(dc1[i - 262144]);
    else if (i < 393216)     WB[i] = f2bf(dc2[i - 327680]);
    else if (i < 394240)     WB[i] = f2bf(ds2[i - 393216]);
    else if (i < 459776) {   // Wzr [256][256]: rows 0-127 = [f1u|f2u], 128-255 = [f1r|f2r]
        int j = i - 394240, row = j >> 8, c = j & 255;
        float v;
        if (row < 128) v = (c < 128) ? f1u[row * 128 + c] : f2u[row * 128 + c - 128];
        else { int rr = row - 128; v = (c < 128) ? f1r[rr * 128 + c] : f2r[rr * 128 + c - 128]; }
        WB[i] = f2bf(v);
    } else if (i < 492544) { // Wo [128][256] = [f1|f2]
        int j = i - 459776, row = j >> 8, c = j & 255;
        float v = (c < 128) ? f1[row * 128 + c] : f2[row * 128 + c - 128];
        WB[i] = f2bf(v);
    } else if (i < 492800) {
        int o = i - 492544;
        bzr[o] = (o < 128) ? (f1ub[o] + f2ub[o]) : (f1rb[o - 128] + f2rb[o - 128]);
    } else if (i < 492928) {
        int o = i - 492800;
        bo[o] = f1b[o] + f2b[o];
    }
}

__global__ void cvt_f32_bf16(const float* __restrict__ in, unsigned short* __restrict__ out, int n)
{
    int i = (blockIdx.x * 256 + threadIdx.x) * 4;
    if (i < n) {
        float4 v = *reinterpret_cast<const float4*>(&in[i]);
        out[i] = f2bf(v.x); out[i + 1] = f2bf(v.y);
        out[i + 2] = f2bf(v.z); out[i + 3] = f2bf(v.w);
    }
}

// ================= BN finalize =================================================
__global__ void bn_finalize_kernel(const float* __restrict__ s1, const float* __restrict__ s2,
                                   const float* __restrict__ g, const float* __restrict__ bt,
                                   float* __restrict__ scale, float* __restrict__ shift,
                                   int C, float invN)
{
    int c = threadIdx.x;
    if (c < C) {
        float m = s1[c] * invN;
        float v = fmaxf(s2[c] * invN - m * m, 0.f);
        float sc = g[c] * rsqrtf(v + BN_EPS);
        scale[c] = sc;
        shift[c] = bt[c] - m * sc;
    }
}

// ================= edge gather (bf16 in, bf16 out, fused BN) ===================
__global__ void edge_gather_bf(const unsigned short* __restrict__ pre, const int* __restrict__ vidx,
                               const float* __restrict__ we, const float* __restrict__ scl,
                               const float* __restrict__ shf, unsigned short* __restrict__ ef, int C)
{
    const int tpe = C >> 1;                       // threads per edge
    const int epb = 256 / tpe;                    // edges per block
    const int e = blockIdx.x * epb + threadIdx.x / tpe;
    const int cp = (threadIdx.x % tpe) << 1;
    if (e >= ME) return;
    float s0 = 0.f, s1v = 0.f;
    const int* vi = vidx + e * KE;
    #pragma unroll
    for (int k = 0; k < KE; ++k) {
        int v = vi[k];
        u16x2 u = *(const u16x2*)&pre[(size_t)v * C + cp];
        s0 += bf2f(u.x); s1v += bf2f(u.y);
    }
    float wv = we[e] * (1.0f / KE);
    u16x2 o;
    o.x = f2bf(wv * (scl[cp] * s0 + (float)KE * shf[cp]));
    o.y = f2bf(wv * (scl[cp + 1] * s1v + (float)KE * shf[cp + 1]));
    *(u16x2*)&ef[(size_t)e * C + cp] = o;
}

// f32 variant for C == 2 (dis2 path)
__global__ void edge_gather2_kernel(const float* __restrict__ X, const int* __restrict__ vidx,
                                    const float* __restrict__ we, const float* __restrict__ scale,
                                    const float* __restrict__ shift, float* __restrict__ ef)
{
    int e = blockIdx.x * blockDim.x + threadIdx.x;
    if (e >= ME) return;
    float s0 = 0.f, s1v = 0.f;
    #pragma unroll
    for (int k = 0; k < KE; ++k) {
        int v = vidx[e * KE + k];
        s0 += X[2 * v];
        s1v += X[2 * v + 1];
    }
    float w = we[e] * (1.0f / KE);
    ef[2 * e]     = w * (scale[0] * s0 + (float)KE * shift[0]);
    ef[2 * e + 1] = w * (scale[1] * s1v + (float)KE * shift[1]);
}

// ================= CSR build ===================================================
__global__ void deg_kernel(const int* __restrict__ vidx, int* __restrict__ deg)
{
    int i = blockIdx.x * blockDim.x + threadIdx.x;
    if (i < ME * KE) atomicAdd(&deg[vidx[i]], 1);
}

__global__ void scan_block_kernel(const int* __restrict__ deg, int* __restrict__ rowptr,
                                  int* __restrict__ blocksums, int n)
{
    __shared__ int tmp[256];
    int i = blockIdx.x * 256 + threadIdx.x;
    int v = (i < n) ? deg[i] : 0;
    tmp[threadIdx.x] = v;
    __syncthreads();
    for (int off = 1; off < 256; off <<= 1) {
        int t = (threadIdx.x >= off) ? tmp[threadIdx.x - off] : 0;
        __syncthreads();
        tmp[threadIdx.x] += t;
        __syncthreads();
    }
    if (i < n) rowptr[i] = tmp[threadIdx.x] - v;
    if (threadIdx.x == 255) blocksums[blockIdx.x] = tmp[255];
}

__global__ void scan_sums_kernel(int* __restrict__ blocksums, int nb)
{
    if (threadIdx.x == 0 && blockIdx.x == 0) {
        int acc = 0;
        for (int b = 0; b < nb; ++b) { int t = blocksums[b]; blocksums[b] = acc; acc += t; }
    }
}

__global__ void scan_add_kernel(int* __restrict__ rowptr, const int* __restrict__ blocksums, int n)
{
    int i = blockIdx.x * 256 + threadIdx.x;
    if (i < n) rowptr[i] += blocksums[blockIdx.x];
    if (i == 0) rowptr[n] = ME * KE;
}

__global__ void csr_fill_kernel(const int* __restrict__ vidx, int* __restrict__ cursor,
                                int* __restrict__ csr)
{
    int i = blockIdx.x * blockDim.x + threadIdx.x;
    if (i < ME * KE) {
        int v = vidx[i];
        int pos = atomicAdd(&cursor[v], 1);
        csr[pos] = i >> 4;
    }
}

// ================= e->v via CSR gather (bf16 ef), fused /deg (+relu) ===========
__global__ __launch_bounds__(256)
void csr_gather_bf(const unsigned short* __restrict__ ef, const int* __restrict__ rowptr,
                   const int* __restrict__ csr,
                   float* __restrict__ outf, int ldf,
                   unsigned short* __restrict__ outb, int ldb, int cb0,
                   unsigned short* __restrict__ outb2, int ldb2,
                   int C, int relu)
{
    const int lpv = C >> 3;                      // lanes per vertex (8 cols each)
    const int vpb = 256 / lpv;
    const int v = blockIdx.x * vpb + threadIdx.x / lpv;
    const int lg = threadIdx.x % lpv;
    if (v >= NV) return;
    const int s = rowptr[v], e = rowptr[v + 1];
    float a[8] = {};
    for (int i = s; i < e; ++i) {
        int ed = csr[i];
        u16x8 u = *(const u16x8*)&ef[(size_t)ed * C + lg * 8];
        #pragma unroll
        for (int j = 0; j < 8; ++j) a[j] += bf2f(u[j]);
    }
    float inv = 1.0f / (float)max(e - s, 1);
    #pragma unroll
    for (int j = 0; j < 8; ++j) {
        float x = a[j] * inv;
        if (relu) x = fmaxf(x, 0.f);
        a[j] = x;
    }
    if (outf) {
        float* p = outf + (size_t)v * ldf + lg * 8;
        #pragma unroll
        for (int j = 0; j < 8; ++j) p[j] = a[j];
    }
    if (outb) {
        u16x8 o;
        #pragma unroll
        for (int j = 0; j < 8; ++j) o[j] = f2bf(a[j]);
        *(u16x8*)&outb[(size_t)v * ldb + cb0 + lg * 8] = o;
    }
    if (outb2) {
        u16x8 o;
        #pragma unroll
        for (int j = 0; j < 8; ++j) o[j] = f2bf(a[j]);
        *(u16x8*)&outb2[(size_t)v * ldb2 + lg * 8] = o;
    }
}

__global__ void csr_gather2_kernel(const float* __restrict__ ef, const int* __restrict__ rowptr,
                                   const int* __restrict__ csr, float* __restrict__ outp)
{
    int v = blockIdx.x * blockDim.x + threadIdx.x;
    if (v >= NV) return;
    int s = rowptr[v], e = rowptr[v + 1];
    float a0 = 0.f, a1 = 0.f;
    for (int i = s; i < e; ++i) {
        int ed = csr[i];
        a0 += ef[2 * ed];
        a1 += ef[2 * ed + 1];
    }
    float inv = 1.0f / (float)max(e - s, 1);
    outp[2 * v]     = a0 * inv;
    outp[2 * v + 1] = a1 * inv;
}

// ================= dis2: [N,512] bf16 @ [2,512]^T, one wave per row ============
__global__ __launch_bounds__(256)
void dis2_dot(const unsigned short* __restrict__ A, const unsigned short* __restrict__ Wd,
              const float* __restrict__ bias, float* __restrict__ pre)
{
    const int wid = threadIdx.x >> 6, l = threadIdx.x & 63;
    const int v = blockIdx.x * 4 + wid;
    if (v >= NV) return;
    u16x8 a = *(const u16x8*)&A[(size_t)v * 512 + l * 8];
    u16x8 w0 = *(const u16x8*)&Wd[l * 8];
    u16x8 w1 = *(const u16x8*)&Wd[512 + l * 8];
    float d0 = 0.f, d1 = 0.f;
    #pragma unroll
    for (int j = 0; j < 8; ++j) {
        float av = bf2f(a[j]);
        d0 += av * bf2f(w0[j]);
        d1 += av * bf2f(w1[j]);
    }
    for (int o = 32; o > 0; o >>= 1) {
        d0 += __shfl_down(d0, o);
        d1 += __shfl_down(d1, o);
    }
    if (l == 0) {
        pre[2 * v]     = d0 + bias[0];
        pre[2 * v + 1] = d1 + bias[1];
    }
}

// ================= stats for C==2 / C==128 f32 =================================
__global__ void colstats_kernel(const float* __restrict__ X, int N, int C,
                                float* __restrict__ s1, float* __restrict__ s2,
                                int rowsPerBlock)
{
    const int c = threadIdx.x;
    int r0 = blockIdx.x * rowsPerBlock;
    int r1 = min(N, r0 + rowsPerBlock);
    float a = 0.f, b = 0.f;
    for (int r = r0; r < r1; ++r) {
        float v = X[(size_t)r * C + c];
        a += v;
        b += v * v;
    }
    atomicAdd(&s1[c], a);
    atomicAdd(&s2[c], b);
}

__global__ void colstats2_kernel(const float* __restrict__ X, int N,
                                 float* __restrict__ s1, float* __restrict__ s2)
{
    __shared__ float red[256][4];
    int t = threadIdx.x;
    float a0 = 0, a1 = 0, b0 = 0, b1 = 0;
    for (int r = blockIdx.x * 256 + t; r < N; r += 256 * gridDim.x) {
        float x0 = X[2 * r], x1 = X[2 * r + 1];
        a0 += x0; b0 += x0 * x0;
        a1 += x1; b1 += x1 * x1;
    }
    red[t][0] = a0; red[t][1] = a1; red[t][2] = b0; red[t][3] = b1;
    __syncthreads();
    for (int s = 128; s > 0; s >>= 1) {
        if (t < s)
            for (int j = 0; j < 4; ++j) red[t][j] += red[t + s][j];
        __syncthreads();
    }
    if (t == 0) {
        atomicAdd(&s1[0], red[0][0]);
        atomicAdd(&s1[1], red[0][1]);
        atomicAdd(&s2[0], red[0][2]);
        atomicAdd(&s2[1], red[0][3]);
    }
}

// ================= GRU elementwise =============================================
__global__ void rx_kernel(const unsigned short* __restrict__ ZR, const unsigned short* __restrict__ xeb,
                          unsigned short* __restrict__ G, int n)
{
    int i = blockIdx.x * blockDim.x + threadIdx.x;
    if (i < n) {
        int row = i >> 7, c = i & 127;
        float r = sigm(bf2f(ZR[(size_t)row * 256 + 128 + c]));
        float xe = bf2f(xeb[i]);
        G[(size_t)row * 256 + 128 + c] = f2bf(r * xe);
    }
}

__global__ void gru_out_kernel(const unsigned short* __restrict__ ZR, const unsigned short* __restrict__ Opre,
                               const unsigned short* __restrict__ xeb,
                               float* __restrict__ outs, unsigned short* __restrict__ outsb, int n)
{
    int i = blockIdx.x * blockDim.x + threadIdx.x;
    if (i < n) {
        int row = i >> 7, c = i & 127;
        float z = sigm(bf2f(ZR[(size_t)row * 256 + c]));
        float o = tanhf(bf2f(Opre[i]));
        float xe = bf2f(xeb[i]);
        float val = z * o + (1.f - z) * xe;
        outs[i] = val;
        outsb[i] = f2bf(val);
    }
}

// ================= attention pooling ===========================================
__global__ void att_finalize_kernel(const float* __restrict__ s1, const float* __restrict__ s2,
                                    float* __restrict__ mu, float* __restrict__ qd, int C)
{
    int c = threadIdx.x;
    if (c < C) {
        float m = s1[c] / (float)NV;
        float vv = fmaxf((s2[c] - (float)NV * m * m) / (float)(NV - 1), 0.f);
        mu[c] = m;
        qd[c] = 1.0f / (4.0f * (vv + 0.001f));
    }
}

__global__ void proto_kernel(const float* __restrict__ outs, const float* __restrict__ mu,
                             const float* __restrict__ qd, float* __restrict__ proto,
                             int rowsPerBlock)
{
    const int c = threadIdx.x;  // C = 128
    int r0 = blockIdx.x * rowsPerBlock;
    int r1 = min(NV, r0 + rowsPerBlock);
    float m = mu[c], q = qd[c], acc = 0.f;
    for (int r = r0; r < r1; ++r) {
        float x = outs[(size_t)r * 128 + c];
        float dd = (x - m) * (x - m);
        acc += x * sigm(dd * q + 0.5f);
    }
    atomicAdd(&proto[c], acc);
}

// ==============================================================================
extern "C" void kernel_launch(void* const* d_in, const int* in_sizes, int n_in,
                              void* d_out, int out_size, void* d_ws, size_t ws_size,
                              hipStream_t stream)
{
    const float* X      = (const float*)d_in[0];
    const int*   vidx   = (const int*)  d_in[1];
    const float* we     = (const float*)d_in[2];
    const float* enc1_W = (const float*)d_in[3];  const float* enc1_b = (const float*)d_in[4];
    const float* enc2_W = (const float*)d_in[5];  const float* enc2_b = (const float*)d_in[6];
    const float* fc_W   = (const float*)d_in[7];  const float* fc_b   = (const float*)d_in[8];
    const float* f1u_W  = (const float*)d_in[9];  const float* f1u_b  = (const float*)d_in[10];
    const float* f2u_W  = (const float*)d_in[11]; const float* f2u_b  = (const float*)d_in[12];
    const float* f1r_W  = (const float*)d_in[13]; const float* f1r_b  = (const float*)d_in[14];
    const float* f2r_W  = (const float*)d_in[15]; const float* f2r_b  = (const float*)d_in[16];
    const float* f1_W   = (const float*)d_in[17]; const float* f1_b   = (const float*)d_in[18];
    const float* f2_W   = (const float*)d_in[19]; const float* f2_b   = (const float*)d_in[20];
    const float* dis1_W = (const float*)d_in[21]; const float* dis1_b = (const float*)d_in[22];
    const float* dis2_W = (const float*)d_in[23]; const float* dis2_b = (const float*)d_in[24];
    const float* dec1_W = (const float*)d_in[25]; const float* dec1_b = (const float*)d_in[26];
    const float* dec2_W = (const float*)d_in[27]; const float* dec2_b = (const float*)d_in[28];
    const float* enc1_g = (const float*)d_in[29]; const float* enc1_bt = (const float*)d_in[30];
    const float* enc2_g = (const float*)d_in[31]; const float* enc2_bt = (const float*)d_in[32];
    const float* dis1_g = (const float*)d_in[33]; const float* dis1_bt = (const float*)d_in[34];
    const float* dis2_g = (const float*)d_in[35]; const float* dis2_bt = (const float*)d_in[36];
    const float* dec1_g = (const float*)d_in[37]; const float* dec1_bt = (const float*)d_in[38];
    const float* dec2_g = (const float*)d_in[39]; const float* dec2_bt = (const float*)d_in[40];

    float* out   = (float*)d_out;
    float* outs  = out;                   // [N,128]
    float* x_de  = out + 12800000;        // [N,128]
    float* proto = out + 25600000;        // [128]
    float* xdis  = out + 25600128;        // [N,2]

    // ---------------- workspace layout (bytes) ----------------
    char* base = (char*)d_ws;
    unsigned short* bufA = (unsigned short*)base;                 // [NP,512] bf16 (pre/ZR/Opre/xe_bf)
    char* p = base + (size_t)NP * 512 * 2;
    unsigned short* bufE = (unsigned short*)p; p += (size_t)ME * 512 * 2;   // edge features bf16
    unsigned short* Greg = (unsigned short*)p;                    // [NP,256] bf16, overlays Xbf|outs_bf
    unsigned short* Xbf  = Greg;                                  // [NP,128]
    unsigned short* outsb = Greg + (size_t)NP * 128;              // [NP,128]
    p += (size_t)NP * 256 * 2;
    unsigned short* x1bf = (unsigned short*)p; p += (size_t)NP * 512 * 2;   // x1 / hdis / hdec
    unsigned short* WB = (unsigned short*)p; p += 492544 * 2 + 1024;
    float* bzr = (float*)p; p += 256 * 4;
    float* bo  = (float*)p; p += 128 * 4;
    float* s1  = (float*)p; p += 512 * 4;
    float* s2  = (float*)p; p += 512 * 4;
    float* scl = (float*)p; p += 512 * 4;
    float* shf = (float*)p; p += 512 * 4;
    int* deg    = (int*)p; p += (size_t)NV * 4;
    int* rowptr = (int*)p; p += (size_t)(NV + 1) * 4;
    int* cursor = (int*)p; p += (size_t)NV * 4;
    int* bsums  = (int*)p; p += 512 * 4;
    int* csr    = (int*)p;

    // bufA sub-views
    unsigned short* pre512 = bufA;                         // [NP,512]
    unsigned short* pre128 = bufA;                         // [NP,128]
    unsigned short* xe_bf  = bufA + (size_t)NP * 128;      // [NP,128]
    unsigned short* ZR     = bufA + (size_t)NP * 256;      // [NP,256]
    unsigned short* Opre   = bufA;                         // [NP,128] (reuses pre128)
    float* pre22 = (float*)bufA;                           // [N,2] f32 (dis2 pre)
    float* bufEf = (float*)bufE;                           // [M,2] f32 view

    // weight sub-offsets (ushort)
    unsigned short* wenc1 = WB;
    unsigned short* wenc2 = WB + 65536;
    unsigned short* wfc   = WB + 131072;
    unsigned short* wdis1 = WB + 196608;
    unsigned short* wdec1 = WB + 262144;
    unsigned short* wdec2 = WB + 327680;
    unsigned short* wdis2 = WB + 393216;
    unsigned short* wzr   = WB + 394240;
    unsigned short* wo    = WB + 459776;

    const int n128 = NV * 128;
    const int nScanBlocks = (NV + 255) / 256;

    auto gemm = [&](const unsigned short* A, int ic, const unsigned short* W, const float* b,
                    unsigned short* Cb, int ldb, int cb0, int oc, float* st1, float* st2) {
        dim3 g(oc / 64, NP / 128);
        mfma_gemm<<<g, 256, 0, stream>>>(A, ic, W, b, Cb, ldb, cb0, st1, st2);
    };

    // ---- prep: weights + X conversion ----
    prep_weights<<<1926, 256, 0, stream>>>(enc1_W, enc2_W, fc_W, dis1_W, dec1_W, dec2_W, dis2_W,
                                           f1u_W, f2u_W, f1r_W, f2r_W, f1_W, f2_W,
                                           f1u_b, f2u_b, f1r_b, f2r_b, f1_b, f2_b,
                                           WB, bzr, bo);
    cvt_f32_bf16<<<(n128 / 4 + 255) / 256, 256, 0, stream>>>(X, Xbf, n128);

    // ---- build CSR ----
    hipMemsetAsync(deg, 0, NV * sizeof(int), stream);
    deg_kernel<<<(ME * KE + 255) / 256, 256, 0, stream>>>(vidx, deg);
    scan_block_kernel<<<nScanBlocks, 256, 0, stream>>>(deg, rowptr, bsums, NV);
    scan_sums_kernel<<<1, 64, 0, stream>>>(bsums, nScanBlocks);
    scan_add_kernel<<<nScanBlocks, 256, 0, stream>>>(rowptr, bsums, NV);
    hipMemcpyAsync(cursor, rowptr, NV * sizeof(int), hipMemcpyDeviceToDevice, stream);
    csr_fill_kernel<<<(ME * KE + 255) / 256, 256, 0, stream>>>(vidx, cursor, csr);

    auto bn_eg = [&](const unsigned short* pre, int C, const float* g_, const float* bt_) {
        bn_finalize_kernel<<<1, 512, 0, stream>>>(s1, s2, g_, bt_, scl, shf, C, 1.0f / NV);
        int tpe = C >> 1, epb = 256 / tpe;
        edge_gather_bf<<<(ME + epb - 1) / epb, 256, 0, stream>>>(pre, vidx, we, scl, shf, bufE, C);
    };

    // ---- conv1 (enc1): pre512 -> x1bf (relu) ----
    hipMemsetAsync(s1, 0, 1024 * sizeof(float), stream);
    gemm(Xbf, 128, wenc1, enc1_b, pre512, 512, 0, 512, s1, s2);
    bn_eg(pre512, 512, enc1_g, enc1_bt);
    csr_gather_bf<<<NV / 4, 256, 0, stream>>>(bufE, rowptr, csr,
        nullptr, 0, x1bf, 512, 0, nullptr, 0, 512, 1);

    // ---- conv2 (enc2): pre128 -> xe (G right half + xe_bf) ----
    hipMemsetAsync(s1, 0, 1024 * sizeof(float), stream);
    gemm(x1bf, 512, wenc2, enc2_b, pre128, 128, 0, 128, s1, s2);
    bn_eg(pre128, 128, enc2_g, enc2_bt);
    csr_gather_bf<<<NV / 16, 256, 0, stream>>>(bufE, rowptr, csr,
        nullptr, 0, Greg, 256, 128, xe_bf, 128, 128, 0);

    // ---- xe1 = x1 @ fc^T + b -> G left half ----
    gemm(x1bf, 512, wfc, fc_b, Greg, 256, 0, 128, nullptr, nullptr);

    // ---- GRU ----
    gemm(Greg, 256, wzr, bzr, ZR, 256, 0, 256, nullptr, nullptr);
    rx_kernel<<<(n128 + 255) / 256, 256, 0, stream>>>(ZR, xe_bf, Greg, n128);
    gemm(Greg, 256, wo, bo, Opre, 128, 0, 128, nullptr, nullptr);
    gru_out_kernel<<<(n128 + 255) / 256, 256, 0, stream>>>(ZR, Opre, xe_bf, outs, outsb, n128);

    // ---- attention pooling -> proto ----
    hipMemsetAsync(s1, 0, 1024 * sizeof(float), stream);
    colstats_kernel<<<400, 128, 0, stream>>>(outs, NV, 128, s1, s2, 250);
    att_finalize_kernel<<<1, 128, 0, stream>>>(s1, s2, scl, shf, 128);
    hipMemsetAsync(proto, 0, 128 * sizeof(float), stream);
    proto_kernel<<<400, 128, 0, stream>>>(outs, scl, shf, proto, 250);

    // ---- discriminator branch ----
    hipMemsetAsync(s1, 0, 1024 * sizeof(float), stream);
    gemm(outsb, 128, wdis1, dis1_b, pre512, 512, 0, 512, s1, s2);
    bn_eg(pre512, 512, dis1_g, dis1_bt);
    csr_gather_bf<<<NV / 4, 256, 0, stream>>>(bufE, rowptr, csr,
        nullptr, 0, x1bf, 512, 0, nullptr, 0, 512, 1);          // hdis -> x1bf
    dis2_dot<<<NV / 4, 256, 0, stream>>>(x1bf, wdis2, dis2_b, pre22);
    hipMemsetAsync(s1, 0, 1024 * sizeof(float), stream);
    colstats2_kernel<<<64, 256, 0, stream>>>(pre22, NV, s1, s2);
    bn_finalize_kernel<<<1, 512, 0, stream>>>(s1, s2, dis2_g, dis2_bt, scl, shf, 2, 1.0f / NV);
    edge_gather2_kernel<<<(ME + 255) / 256, 256, 0, stream>>>(pre22, vidx, we, scl, shf, bufEf);
    csr_gather2_kernel<<<(NV + 255) / 256, 256, 0, stream>>>(bufEf, rowptr, csr, xdis);

    // ---- decoder branch ----
    hipMemsetAsync(s1, 0, 1024 * sizeof(float), stream);
    gemm(outsb, 128, wdec1, dec1_b, pre512, 512, 0, 512, s1, s2);
    bn_eg(pre512, 512, dec1_g, dec1_bt);
    csr_gather_bf<<<NV / 4, 256, 0, stream>>>(bufE, rowptr, csr,
        nullptr, 0, x1bf, 512, 0, nullptr, 0, 512, 1);          // hdec -> x1bf
    hipMemsetAsync(s1, 0, 1024 * sizeof(float), stream);
    gemm(x1bf, 512, wdec2, dec2_b, pre128, 128, 0, 128, s1, s2);
    bn_eg(pre128, 128, dec2_g, dec2_bt);
    csr_gather_bf<<<NV / 16, 256, 0, stream>>>(bufE, rowptr, csr,
        x_de, 128, nullptr, 0, 0, nullptr, 0, 128, 0);
}